// Round 6
// baseline (344.034 us; speedup 1.0000x reference)
//
#include <hip/hip_runtime.h>

// ---------------------------------------------------------------------------
// VisualContrastiveLoss on MI355X
// loss = C + mean_i log(Z_i) - mean_i sim[i, lab_i],  C = 1/0.07
//   Z_i = sum_j exp(sim_ij - C)  (fixed shift: dots bounded by 1)
//   sim = (f f^T)/0.07, f = row-normalized visual_feat
// R14: SYMMETRY — compute only tiles J >= I (2080/4096).
// R16/R17: tile-per-block + global B-gather REGRESSED: B must be LDS-
//   broadcast; multi-tile blocks amortize; balance via grid decomposition.
// R18/R19: A-frags-in-registers SHELVED: allocator pins VGPR=128 and spills
//   (FETCH 202MB/WRITE 145MB) under both __launch_bounds__(256,2) and
//   amdgpu_waves_per_eu(2,2). Finalize 8-block ticket KEPT (-2us, passed).
// R20: 3 BLOCKS/CU — round-0 skeleton (proven 37us sim: stage->sync->
//   MFMA->sync per kk, single-buffered B) with LDS 80->48KB:
//   * ldsA = 2-plane double-buffer (32KB); plane (kk+1)&3 re-staged per
//     phase kk alongside B, into ldsA[(kk+1)&1] (last read at phase kk-1,
//     protected by the existing trailing barrier). A restage = L2 traffic,
//     ~3us/CU, drained by the same __syncthreads.
//   * grid (64,16): J-stride 16, 1024 blocks of <=4 tiles; I = bx flipped
//     per by-row for heavy/light pairing. 3 blocks/CU (launch_bounds 256,3).
//   Pipe budget/CU: MFMA 18k cyc, LDS-read 25k, VALU 17k, staging 8k ->
//   sum 68k=28us; round-0 at 2 blk/CU measured 37us (no overlap). 3rd
//   block should hide barrier/drain phases -> predict sim ~28-31us.
// ---------------------------------------------------------------------------

typedef int i32x8 __attribute__((ext_vector_type(8)));
typedef float f32x4 __attribute__((ext_vector_type(4)));

#define B_N 8192
#define D_K 512
#define ROWB 512  // bytes per fp8 row
#define INVT 14.285714285714286f
// (1/0.07) * log2(e)
#define SCALE_LOG2 20.609929155556622f

#if defined(__has_builtin) && __has_builtin(__builtin_amdgcn_exp2f)
#define FAST_EXP2(x) __builtin_amdgcn_exp2f(x)
#else
#define FAST_EXP2(x) exp2f(x)
#endif

union FragU {
  int4 h[2];
  i32x8 v;
};

static __device__ __forceinline__ void load16_to_lds(const void* g, void* l) {
  __builtin_amdgcn_global_load_lds(
      (const __attribute__((address_space(1))) unsigned int*)g,
      (__attribute__((address_space(3))) unsigned int*)l, 16, 0, 0);
}

// ---- K1: 4 waves/block, one wave per row; normalize fp32 -> fp8 e4m3 --------
// Also zeroes Z, S, ticket (ws is poisoned before every launch).
__global__ __launch_bounds__(256)
void norm_kernel(const float* __restrict__ x,
                 unsigned char* __restrict__ fQ,
                 float* __restrict__ Z,
                 float* __restrict__ S,
                 int* __restrict__ ticket) {
  const int row = blockIdx.x * 4 + (threadIdx.x >> 6);
  const int lane = threadIdx.x & 63;
  const float4* xr = (const float4*)(x + (size_t)row * D_K);
  float4 a = xr[2 * lane];
  float4 b = xr[2 * lane + 1];
  float s = a.x * a.x + a.y * a.y + a.z * a.z + a.w * a.w +
            b.x * b.x + b.y * b.y + b.z * b.z + b.w * b.w;
#pragma unroll
  for (int off = 1; off < 64; off <<= 1) s += __shfl_xor(s, off);
  const float inv = 1.0f / fmaxf(sqrtf(s), 1e-12f);
  int lo = 0, hi = 0;
  lo = __builtin_amdgcn_cvt_pk_fp8_f32(a.x * inv, a.y * inv, lo, false);
  lo = __builtin_amdgcn_cvt_pk_fp8_f32(a.z * inv, a.w * inv, lo, true);
  hi = __builtin_amdgcn_cvt_pk_fp8_f32(b.x * inv, b.y * inv, hi, false);
  hi = __builtin_amdgcn_cvt_pk_fp8_f32(b.z * inv, b.w * inv, hi, true);
  int2 p; p.x = lo; p.y = hi;
  ((int2*)(fQ + (size_t)row * ROWB))[lane] = p;
  if (lane == 0) Z[row] = 0.0f;
  if (blockIdx.x == 0 && threadIdx.x == 0) {
    S[0] = 0.0f;
    ticket[0] = 0;
  }
}

// ---- K2: upper-triangular fp8 similarity + softmax-denominator --------------
// grid (64,16): I = bx (flipped on odd by), b = by; tiles J in {J >= I,
// J == b mod 16}. 4 waves 2x2; wave owns 64x64 C via 4x4 frags of
// 16x16x128 MX-fp8 MFMA (scale=1). Granule layout per 128B chunk: slot s
// of row r holds global granule h(s^(r&7)), h(u)=2(u&3)+(u>>2); frag reads
// at slots (q)^swz,(q+4)^swz -> granules 2q,2q+1, zero conflicts.
// A K-planes double-buffered (plane kk+1 staged during phase kk); B single
// buffer staged at phase start; two __syncthreads per phase (round-0).
__global__ __launch_bounds__(256, 3)
void sim_kernel(const unsigned char* __restrict__ fQ,
                float* __restrict__ Z, float* __restrict__ T01,
                float* __restrict__ D) {
  __shared__ unsigned char ldsA[2][128 * 128];  // 32 KB: A plane dbuf
  __shared__ unsigned char ldsB[128 * 128];     // 16 KB

  const int tid = threadIdx.x;
  const int lane = tid & 63;
  const int w = tid >> 6;
  const int wm = w & 1;       // wave row strip (0/1) -> rows wm*64..
  const int wn = w >> 1;      // wave col strip (0/1) -> cols wn*64..
  const int bx = blockIdx.x, by = blockIdx.y;
  const int I = (by & 1) ? (63 - bx) : bx;     // row band index (paired)
  const int Jfirst = I + ((by - I) & 15);      // first J >= I, J==by (mod 16)
  if (Jfirst > 63) return;                     // no tiles for this block
  const int I0 = I * 128;

  // staging lane geometry: 8 rows x 8 slots(16B) per instruction.
  const int srow = lane >> 3;                 // 0..7
  const int sb = lane & 7;                    // dest slot
  const int su = sb ^ srow;
  const int sg = 2 * (su & 3) + (su >> 2);    // source granule
  const size_t sOff = (size_t)srow * ROWB + sg * 16;  // bytes

  // fragment-read lane geometry
  const int fr = lane & 15;   // M/N index within 16
  const int q = lane >> 4;    // quad -> k chunk of 32B
  const int swz = fr & 7;     // row&7 of the frag row

  const int raRow = (wm * 64 + fr) * 128;
  const unsigned char* rbBase = ldsB + (wn * 64 + fr) * 128;
  const int off0 = (q ^ swz) * 16;        // slot holding granule 2q
  const int off1 = ((q + 4) ^ swz) * 16;  // slot holding granule 2q+1

  // ---- prologue: stage A plane 0 into ldsA[0] ------------------------------
  {
    const unsigned char* gA = fQ + (size_t)(I0 + w * 32) * ROWB + sOff;
    unsigned char* lA = ldsA[0] + (w * 32) * 128;
#pragma unroll
    for (int rr = 0; rr < 32; rr += 8)
      load16_to_lds(gA + (size_t)rr * ROWB, lA + rr * 128);
  }

  float Zp[4][4];
#pragma unroll
  for (int m = 0; m < 4; ++m)
#pragma unroll
    for (int r = 0; r < 4; ++r) Zp[m][r] = 0.0f;

#pragma unroll 1
  for (int J = Jfirst; J < 64; J += 16) {
    const int J0 = J * 128;
    f32x4 acc[4][4];
#pragma unroll
    for (int m = 0; m < 4; ++m)
#pragma unroll
      for (int n = 0; n < 4; ++n) acc[m][n] = (f32x4){0.f, 0.f, 0.f, 0.f};

#pragma unroll
    for (int kk = 0; kk < 4; ++kk) {
      {  // B: 128 rows of chunk kk, wave stages rows w*32..+31 (4 instrs)
        const unsigned char* gB =
            fQ + (size_t)(J0 + w * 32) * ROWB + kk * 128 + sOff;
        unsigned char* lB = ldsB + (w * 32) * 128;
#pragma unroll
        for (int rr = 0; rr < 32; rr += 8)
          load16_to_lds(gB + (size_t)rr * ROWB, lB + rr * 128);
      }
      {  // A: plane (kk+1)&3 into the other buffer (read at phase kk+1;
         // that buffer's last readers finished at phase kk-1's barrier)
        const int p = (kk + 1) & 3;
        const unsigned char* gA =
            fQ + (size_t)(I0 + w * 32) * ROWB + p * 128 + sOff;
        unsigned char* lA = ldsA[(kk + 1) & 1] + (w * 32) * 128;
#pragma unroll
        for (int rr = 0; rr < 32; rr += 8)
          load16_to_lds(gA + (size_t)rr * ROWB, lA + rr * 128);
      }
      __syncthreads();  // drains vmcnt: B(kk) + A(kk+1) staged; A(kk) ready

      const unsigned char* raBase = ldsA[kk & 1] + raRow;
      i32x8 bv[4];
#pragma unroll
      for (int n = 0; n < 4; ++n) {
        const unsigned char* rb = rbBase + n * 16 * 128;
        FragU u;
        u.h[0] = *(const int4*)(rb + off0);
        u.h[1] = *(const int4*)(rb + off1);
        bv[n] = u.v;
      }
#pragma unroll
      for (int mh = 0; mh < 2; ++mh) {  // m-split: av[2] live, not av[4]
        i32x8 av[2];
#pragma unroll
        for (int m = 0; m < 2; ++m) {
          const unsigned char* ra = raBase + (mh * 2 + m) * 16 * 128;
          FragU u;
          u.h[0] = *(const int4*)(ra + off0);
          u.h[1] = *(const int4*)(ra + off1);
          av[m] = u.v;
        }
#pragma unroll
        for (int m = 0; m < 2; ++m)
#pragma unroll
          for (int n = 0; n < 4; ++n)
            acc[mh * 2 + m][n] = __builtin_amdgcn_mfma_scale_f32_16x16x128_f8f6f4(
                av[m], bv[n], acc[mh * 2 + m][n], 0, 0, 0, 127, 0, 127);
      }
      __syncthreads();  // all waves done reading ldsB / ldsA[(kk+1)&1]'s old
    }

    // T01: sim[0,c], sim[1,c] from rows 0,1 (band I==0 only; rows 0,1 live
    // in wm==0, frag m=0, q==0, r in {0,1}; col c = J0 + wn*64 + n*16 + fr)
    if (I == 0 && wm == 0) {
      if (q == 0) {
#pragma unroll
        for (int n = 0; n < 4; ++n) {
          const int col = J0 + wn * 64 + n * 16 + fr;
          T01[col * 2 + 0] = acc[0][n][0] * INVT;
          T01[col * 2 + 1] = acc[0][n][1] * INVT;
        }
      }
    }

    // D: diagonal dots, from the diagonal tile only
    if (J == I) {
#pragma unroll
      for (int m = 0; m < 4; ++m)
#pragma unroll
        for (int n = 0; n < 4; ++n) {
          const int col = J0 + wn * 64 + n * 16 + fr;
#pragma unroll
          for (int r = 0; r < 4; ++r) {
            const int row = I0 + wm * 64 + m * 16 + q * 4 + r;
            if (row == col) D[row] = acc[m][n][r];
          }
        }
    }

    // Z: row partials always (covers this tile's rows); column sums for
    // off-diag tiles (transpose contribution to Z[J-band]).
    const bool offd = (J != I);
#pragma unroll
    for (int n = 0; n < 4; ++n) {
      float cs = 0.0f;
#pragma unroll
      for (int m = 0; m < 4; ++m)
#pragma unroll
        for (int r = 0; r < 4; ++r) {
          const float e = FAST_EXP2((acc[m][n][r] - 1.0f) * SCALE_LOG2);
          Zp[m][r] += e;
          cs += e;
        }
      if (offd) {
        cs += __shfl_xor(cs, 16);
        cs += __shfl_xor(cs, 32);
        if (q == 0) atomicAdd(&Z[J0 + wn * 64 + n * 16 + fr], cs);
      }
    }
  }

  // row sums: reduce Zp across the 16 col-lanes, then atomicAdd
#pragma unroll
  for (int m = 0; m < 4; ++m)
#pragma unroll
    for (int r = 0; r < 4; ++r) {
      float v = Zp[m][r];
      v += __shfl_xor(v, 1);
      v += __shfl_xor(v, 2);
      v += __shfl_xor(v, 4);
      v += __shfl_xor(v, 8);
      if (fr == 0) atomicAdd(&Z[I0 + wm * 64 + m * 16 + q * 4 + r], v);
    }
}

// ---- K3: labels + exact-diagonal fixup + loss reduction (8 blocks) ----------
// 8 blocks x 1024 threads, 1 row each; block partial -> device atomicAdd;
// last block (ticket) writes the final scaled loss.
__global__ __launch_bounds__(1024)
void finalize_kernel(const float* __restrict__ Z,
                     const float* __restrict__ T01,
                     const float* __restrict__ D,
                     const int* __restrict__ ids,
                     const int* __restrict__ anchor,
                     float* __restrict__ S,
                     int* __restrict__ ticket,
                     float* __restrict__ out) {
  __shared__ float red[16];
  const int t = threadIdx.x;
  const int row = blockIdx.x * 1024 + t;
  const int anchor_id = ids[anchor[0]];
  const int sameLast = (ids[B_N - 1] == anchor_id);
  const int samePrev = (ids[B_N - 2] == anchor_id);
  const float z = Z[row];
  const float d = D[row];
  const float t0 = T01[row * 2 + 0];
  const float t1 = T01[row * 2 + 1];
  const int id = ids[row];

  const int same_i = (id == anchor_id);
  const int lab = (row < B_N - 1) ? (same_i & sameLast) : (sameLast & samePrev);
  const float tt = lab ? t1 : t0;
  // replace quantized diag contribution with the exact value exp(0)=1
  const float Zc = z - FAST_EXP2((d - 1.0f) * SCALE_LOG2) + 1.0f;
  float sum = tt - (INVT + logf(Zc));

#pragma unroll
  for (int off = 1; off < 64; off <<= 1) sum += __shfl_xor(sum, off);
  if ((t & 63) == 0) red[t >> 6] = sum;
  __syncthreads();
  if (t < 64) {
    float v = (t < 16) ? red[t] : 0.0f;
#pragma unroll
    for (int off = 1; off < 16; off <<= 1) v += __shfl_xor(v, off);
    if (t == 0) {
      atomicAdd(S, v);
      __threadfence();
      const int old = atomicAdd(ticket, 1);
      if (old == 7) {
        const float tot = atomicAdd(S, 0.0f);  // device-scope coherent read
        out[0] = -tot / (float)B_N;
      }
    }
  }
}

// ---------------------------------------------------------------------------
extern "C" void kernel_launch(void* const* d_in, const int* in_sizes, int n_in,
                              void* d_out, int out_size, void* d_ws, size_t ws_size,
                              hipStream_t stream) {
  const float* x = (const float*)d_in[0];
  const int* ids = (const int*)d_in[1];
  const int* anchor = (const int*)d_in[2];
  float* out = (float*)d_out;

  unsigned char* fQ = (unsigned char*)d_ws;                    // 4 MB fp8
  float* Z = (float*)((char*)d_ws + (size_t)B_N * ROWB);       // 32 KB
  float* T01 = Z + B_N;                                        // 64 KB
  float* D = T01 + 2 * B_N;                                    // 32 KB
  float* S = D + B_N;                                          // 4 B
  int* ticket = (int*)(S + 1);                                 // 4 B

  norm_kernel<<<B_N / 4, 256, 0, stream>>>(x, fQ, Z, S, ticket);
  sim_kernel<<<dim3(64, 16), 256, 0, stream>>>(fQ, Z, T01, D);
  finalize_kernel<<<8, 1024, 0, stream>>>(Z, T01, D, ids, anchor, S, ticket, out);
}

// Round 7
// 202.901 us; speedup vs baseline: 1.6956x; 1.6956x over previous
//
#include <hip/hip_runtime.h>

// ---------------------------------------------------------------------------
// VisualContrastiveLoss on MI355X
// loss = C + mean_i log(Z_i) - mean_i sim[i, lab_i],  C = 1/0.07
//   Z_i = sum_j exp(sim_ij - C)  (fixed shift: dots bounded by 1)
//   sim = (f f^T)/0.07, f = row-normalized visual_feat
// R14: SYMMETRY — compute only tiles J >= I (2080/4096).
// R16/R17: tile-per-block + global B-gather REGRESSED: B must be LDS-
//   broadcast; multi-tile blocks amortize; balance via grid decomposition.
// R18/R19: A-frags-in-registers SHELVED: allocator pins VGPR and spills.
// R20: 3-blocks/CU structure (48KB LDS: A-plane dbuf + J-stride-16 grid)
//   REGRESSED via the SAME failure: __launch_bounds__(256,3) made the
//   allocator target 84 VGPR (6 waves/EU budget — pointless, LDS caps at 3
//   blocks/CU) and SPILL acc[4][4] (FETCH 425MB/WRITE 480MB). The
//   occupancy theory was never tested.
// R21: R20 with ONE change — __launch_bounds__(256,2), which on this body
//   produced VGPR=128/no-spill three times (round-0, R15, R16). 128 VGPR
//   allows 4 waves/SIMD > the 3 blocks/CU LDS cap, so nothing is lost.
//   Expected: VGPR 128, WRITE back to ~KB, Occupancy ~30%, sim ~30us.
//   Pre-committed fallback: if spill persists, revert to round-0 + 8-block
//   finalize (safe ~99us).
// ---------------------------------------------------------------------------

typedef int i32x8 __attribute__((ext_vector_type(8)));
typedef float f32x4 __attribute__((ext_vector_type(4)));

#define B_N 8192
#define D_K 512
#define ROWB 512  // bytes per fp8 row
#define INVT 14.285714285714286f
// (1/0.07) * log2(e)
#define SCALE_LOG2 20.609929155556622f

#if defined(__has_builtin) && __has_builtin(__builtin_amdgcn_exp2f)
#define FAST_EXP2(x) __builtin_amdgcn_exp2f(x)
#else
#define FAST_EXP2(x) exp2f(x)
#endif

union FragU {
  int4 h[2];
  i32x8 v;
};

static __device__ __forceinline__ void load16_to_lds(const void* g, void* l) {
  __builtin_amdgcn_global_load_lds(
      (const __attribute__((address_space(1))) unsigned int*)g,
      (__attribute__((address_space(3))) unsigned int*)l, 16, 0, 0);
}

// ---- K1: 4 waves/block, one wave per row; normalize fp32 -> fp8 e4m3 --------
// Also zeroes Z, S, ticket (ws is poisoned before every launch).
__global__ __launch_bounds__(256)
void norm_kernel(const float* __restrict__ x,
                 unsigned char* __restrict__ fQ,
                 float* __restrict__ Z,
                 float* __restrict__ S,
                 int* __restrict__ ticket) {
  const int row = blockIdx.x * 4 + (threadIdx.x >> 6);
  const int lane = threadIdx.x & 63;
  const float4* xr = (const float4*)(x + (size_t)row * D_K);
  float4 a = xr[2 * lane];
  float4 b = xr[2 * lane + 1];
  float s = a.x * a.x + a.y * a.y + a.z * a.z + a.w * a.w +
            b.x * b.x + b.y * b.y + b.z * b.z + b.w * b.w;
#pragma unroll
  for (int off = 1; off < 64; off <<= 1) s += __shfl_xor(s, off);
  const float inv = 1.0f / fmaxf(sqrtf(s), 1e-12f);
  int lo = 0, hi = 0;
  lo = __builtin_amdgcn_cvt_pk_fp8_f32(a.x * inv, a.y * inv, lo, false);
  lo = __builtin_amdgcn_cvt_pk_fp8_f32(a.z * inv, a.w * inv, lo, true);
  hi = __builtin_amdgcn_cvt_pk_fp8_f32(b.x * inv, b.y * inv, hi, false);
  hi = __builtin_amdgcn_cvt_pk_fp8_f32(b.z * inv, b.w * inv, hi, true);
  int2 p; p.x = lo; p.y = hi;
  ((int2*)(fQ + (size_t)row * ROWB))[lane] = p;
  if (lane == 0) Z[row] = 0.0f;
  if (blockIdx.x == 0 && threadIdx.x == 0) {
    S[0] = 0.0f;
    ticket[0] = 0;
  }
}

// ---- K2: upper-triangular fp8 similarity + softmax-denominator --------------
// grid (64,16): I = bx (flipped on odd by), b = by; tiles J in {J >= I,
// J == b mod 16}. 4 waves 2x2; wave owns 64x64 C via 4x4 frags of
// 16x16x128 MX-fp8 MFMA (scale=1). Granule layout per 128B chunk: slot s
// of row r holds global granule h(s^(r&7)), h(u)=2(u&3)+(u>>2); frag reads
// at slots (q)^swz,(q+4)^swz -> granules 2q,2q+1, zero conflicts.
// A K-planes double-buffered (plane kk+1 staged during phase kk); B single
// buffer staged at phase start; two __syncthreads per phase (round-0).
// LDS 48KB -> 3 blocks/CU; VGPR 128 (launch_bounds(256,2), no spill).
__global__ __launch_bounds__(256, 2)
void sim_kernel(const unsigned char* __restrict__ fQ,
                float* __restrict__ Z, float* __restrict__ T01,
                float* __restrict__ D) {
  __shared__ unsigned char ldsA[2][128 * 128];  // 32 KB: A plane dbuf
  __shared__ unsigned char ldsB[128 * 128];     // 16 KB

  const int tid = threadIdx.x;
  const int lane = tid & 63;
  const int w = tid >> 6;
  const int wm = w & 1;       // wave row strip (0/1) -> rows wm*64..
  const int wn = w >> 1;      // wave col strip (0/1) -> cols wn*64..
  const int bx = blockIdx.x, by = blockIdx.y;
  const int I = (by & 1) ? (63 - bx) : bx;     // row band index (paired)
  const int Jfirst = I + ((by - I) & 15);      // first J >= I, J==by (mod 16)
  if (Jfirst > 63) return;                     // no tiles for this block
  const int I0 = I * 128;

  // staging lane geometry: 8 rows x 8 slots(16B) per instruction.
  const int srow = lane >> 3;                 // 0..7
  const int sb = lane & 7;                    // dest slot
  const int su = sb ^ srow;
  const int sg = 2 * (su & 3) + (su >> 2);    // source granule
  const size_t sOff = (size_t)srow * ROWB + sg * 16;  // bytes

  // fragment-read lane geometry
  const int fr = lane & 15;   // M/N index within 16
  const int q = lane >> 4;    // quad -> k chunk of 32B
  const int swz = fr & 7;     // row&7 of the frag row

  const int raRow = (wm * 64 + fr) * 128;
  const unsigned char* rbBase = ldsB + (wn * 64 + fr) * 128;
  const int off0 = (q ^ swz) * 16;        // slot holding granule 2q
  const int off1 = ((q + 4) ^ swz) * 16;  // slot holding granule 2q+1

  // ---- prologue: stage A plane 0 into ldsA[0] ------------------------------
  {
    const unsigned char* gA = fQ + (size_t)(I0 + w * 32) * ROWB + sOff;
    unsigned char* lA = ldsA[0] + (w * 32) * 128;
#pragma unroll
    for (int rr = 0; rr < 32; rr += 8)
      load16_to_lds(gA + (size_t)rr * ROWB, lA + rr * 128);
  }

  float Zp[4][4];
#pragma unroll
  for (int m = 0; m < 4; ++m)
#pragma unroll
    for (int r = 0; r < 4; ++r) Zp[m][r] = 0.0f;

#pragma unroll 1
  for (int J = Jfirst; J < 64; J += 16) {
    const int J0 = J * 128;
    f32x4 acc[4][4];
#pragma unroll
    for (int m = 0; m < 4; ++m)
#pragma unroll
      for (int n = 0; n < 4; ++n) acc[m][n] = (f32x4){0.f, 0.f, 0.f, 0.f};

#pragma unroll
    for (int kk = 0; kk < 4; ++kk) {
      {  // B: 128 rows of chunk kk, wave stages rows w*32..+31 (4 instrs)
        const unsigned char* gB =
            fQ + (size_t)(J0 + w * 32) * ROWB + kk * 128 + sOff;
        unsigned char* lB = ldsB + (w * 32) * 128;
#pragma unroll
        for (int rr = 0; rr < 32; rr += 8)
          load16_to_lds(gB + (size_t)rr * ROWB, lB + rr * 128);
      }
      {  // A: plane (kk+1)&3 into the other buffer (read at phase kk+1;
         // that buffer's last readers finished at phase kk-1's barrier)
        const int p = (kk + 1) & 3;
        const unsigned char* gA =
            fQ + (size_t)(I0 + w * 32) * ROWB + p * 128 + sOff;
        unsigned char* lA = ldsA[(kk + 1) & 1] + (w * 32) * 128;
#pragma unroll
        for (int rr = 0; rr < 32; rr += 8)
          load16_to_lds(gA + (size_t)rr * ROWB, lA + rr * 128);
      }
      __syncthreads();  // drains vmcnt: B(kk) + A(kk+1) staged; A(kk) ready

      const unsigned char* raBase = ldsA[kk & 1] + raRow;
      i32x8 bv[4];
#pragma unroll
      for (int n = 0; n < 4; ++n) {
        const unsigned char* rb = rbBase + n * 16 * 128;
        FragU u;
        u.h[0] = *(const int4*)(rb + off0);
        u.h[1] = *(const int4*)(rb + off1);
        bv[n] = u.v;
      }
#pragma unroll
      for (int mh = 0; mh < 2; ++mh) {  // m-split: av[2] live, not av[4]
        i32x8 av[2];
#pragma unroll
        for (int m = 0; m < 2; ++m) {
          const unsigned char* ra = raBase + (mh * 2 + m) * 16 * 128;
          FragU u;
          u.h[0] = *(const int4*)(ra + off0);
          u.h[1] = *(const int4*)(ra + off1);
          av[m] = u.v;
        }
#pragma unroll
        for (int m = 0; m < 2; ++m)
#pragma unroll
          for (int n = 0; n < 4; ++n)
            acc[mh * 2 + m][n] = __builtin_amdgcn_mfma_scale_f32_16x16x128_f8f6f4(
                av[m], bv[n], acc[mh * 2 + m][n], 0, 0, 0, 127, 0, 127);
      }
      __syncthreads();  // all waves done reading ldsB / ldsA[(kk+1)&1]'s old
    }

    // T01: sim[0,c], sim[1,c] from rows 0,1 (band I==0 only; rows 0,1 live
    // in wm==0, frag m=0, q==0, r in {0,1}; col c = J0 + wn*64 + n*16 + fr)
    if (I == 0 && wm == 0) {
      if (q == 0) {
#pragma unroll
        for (int n = 0; n < 4; ++n) {
          const int col = J0 + wn * 64 + n * 16 + fr;
          T01[col * 2 + 0] = acc[0][n][0] * INVT;
          T01[col * 2 + 1] = acc[0][n][1] * INVT;
        }
      }
    }

    // D: diagonal dots, from the diagonal tile only
    if (J == I) {
#pragma unroll
      for (int m = 0; m < 4; ++m)
#pragma unroll
        for (int n = 0; n < 4; ++n) {
          const int col = J0 + wn * 64 + n * 16 + fr;
#pragma unroll
          for (int r = 0; r < 4; ++r) {
            const int row = I0 + wm * 64 + m * 16 + q * 4 + r;
            if (row == col) D[row] = acc[m][n][r];
          }
        }
    }

    // Z: row partials always (covers this tile's rows); column sums for
    // off-diag tiles (transpose contribution to Z[J-band]).
    const bool offd = (J != I);
#pragma unroll
    for (int n = 0; n < 4; ++n) {
      float cs = 0.0f;
#pragma unroll
      for (int m = 0; m < 4; ++m)
#pragma unroll
        for (int r = 0; r < 4; ++r) {
          const float e = FAST_EXP2((acc[m][n][r] - 1.0f) * SCALE_LOG2);
          Zp[m][r] += e;
          cs += e;
        }
      if (offd) {
        cs += __shfl_xor(cs, 16);
        cs += __shfl_xor(cs, 32);
        if (q == 0) atomicAdd(&Z[J0 + wn * 64 + n * 16 + fr], cs);
      }
    }
  }

  // row sums: reduce Zp across the 16 col-lanes, then atomicAdd
#pragma unroll
  for (int m = 0; m < 4; ++m)
#pragma unroll
    for (int r = 0; r < 4; ++r) {
      float v = Zp[m][r];
      v += __shfl_xor(v, 1);
      v += __shfl_xor(v, 2);
      v += __shfl_xor(v, 4);
      v += __shfl_xor(v, 8);
      if (fr == 0) atomicAdd(&Z[I0 + wm * 64 + m * 16 + q * 4 + r], v);
    }
}

// ---- K3: labels + exact-diagonal fixup + loss reduction (8 blocks) ----------
// 8 blocks x 1024 threads, 1 row each; block partial -> device atomicAdd;
// last block (ticket) writes the final scaled loss.
__global__ __launch_bounds__(1024)
void finalize_kernel(const float* __restrict__ Z,
                     const float* __restrict__ T01,
                     const float* __restrict__ D,
                     const int* __restrict__ ids,
                     const int* __restrict__ anchor,
                     float* __restrict__ S,
                     int* __restrict__ ticket,
                     float* __restrict__ out) {
  __shared__ float red[16];
  const int t = threadIdx.x;
  const int row = blockIdx.x * 1024 + t;
  const int anchor_id = ids[anchor[0]];
  const int sameLast = (ids[B_N - 1] == anchor_id);
  const int samePrev = (ids[B_N - 2] == anchor_id);
  const float z = Z[row];
  const float d = D[row];
  const float t0 = T01[row * 2 + 0];
  const float t1 = T01[row * 2 + 1];
  const int id = ids[row];

  const int same_i = (id == anchor_id);
  const int lab = (row < B_N - 1) ? (same_i & sameLast) : (sameLast & samePrev);
  const float tt = lab ? t1 : t0;
  // replace quantized diag contribution with the exact value exp(0)=1
  const float Zc = z - FAST_EXP2((d - 1.0f) * SCALE_LOG2) + 1.0f;
  float sum = tt - (INVT + logf(Zc));

#pragma unroll
  for (int off = 1; off < 64; off <<= 1) sum += __shfl_xor(sum, off);
  if ((t & 63) == 0) red[t >> 6] = sum;
  __syncthreads();
  if (t < 64) {
    float v = (t < 16) ? red[t] : 0.0f;
#pragma unroll
    for (int off = 1; off < 16; off <<= 1) v += __shfl_xor(v, off);
    if (t == 0) {
      atomicAdd(S, v);
      __threadfence();
      const int old = atomicAdd(ticket, 1);
      if (old == 7) {
        const float tot = atomicAdd(S, 0.0f);  // device-scope coherent read
        out[0] = -tot / (float)B_N;
      }
    }
  }
}

// ---------------------------------------------------------------------------
extern "C" void kernel_launch(void* const* d_in, const int* in_sizes, int n_in,
                              void* d_out, int out_size, void* d_ws, size_t ws_size,
                              hipStream_t stream) {
  const float* x = (const float*)d_in[0];
  const int* ids = (const int*)d_in[1];
  const int* anchor = (const int*)d_in[2];
  float* out = (float*)d_out;

  unsigned char* fQ = (unsigned char*)d_ws;                    // 4 MB fp8
  float* Z = (float*)((char*)d_ws + (size_t)B_N * ROWB);       // 32 KB
  float* T01 = Z + B_N;                                        // 64 KB
  float* D = T01 + 2 * B_N;                                    // 32 KB
  float* S = D + B_N;                                          // 4 B
  int* ticket = (int*)(S + 1);                                 // 4 B

  norm_kernel<<<B_N / 4, 256, 0, stream>>>(x, fQ, Z, S, ticket);
  sim_kernel<<<dim3(64, 16), 256, 0, stream>>>(fQ, Z, T01, D);
  finalize_kernel<<<8, 1024, 0, stream>>>(Z, T01, D, ids, anchor, S, ticket, out);
}

// Round 8
// 113.357 us; speedup vs baseline: 3.0350x; 1.7899x over previous
//
#include <hip/hip_runtime.h>

// ---------------------------------------------------------------------------
// VisualContrastiveLoss on MI355X
// loss = C + mean_i log(Z_i) - mean_i sim[i, lab_i],  C = 1/0.07
//   Z_i = sum_j exp(sim_ij - C)  (fixed shift: dots bounded by 1)
//   sim = (f f^T)/0.07, f = row-normalized visual_feat
// R14: SYMMETRY — compute only tiles J >= I (2080/4096).
// R16/R17: tile-per-block + global B-gather REGRESSED: B must be LDS-
//   broadcast; multi-tile blocks amortize; balance via grid decomposition.
// R18/R19: A-frags-in-registers SHELVED: allocator pins VGPR and spills.
// R20: __launch_bounds__(256,3) -> allocator targeted 84 VGPR -> spilled acc.
// R21: launch_bounds(256,2) restored VGPR=128 as predicted — but spill
//   PERSISTED (FETCH 140MB/WRITE 167MB). Localized diff vs round-0 (which
//   fits at 128): R20/R21 fully unrolled the kk loop (#pragma unroll) while
//   adding the A-restage block — 4 phases x 2 staging address chains get
//   hoisted across the tile -> dozens of extra live ranges -> spill.
// R22: ONE change — #pragma unroll 1 on the kk loop (round-0's exact form).
//   Keeps: 48KB LDS (A-plane dbuf, restaged per phase inside the rolled
//   loop), grid (64,16) J-stride-16, launch_bounds(256,2), 8-block ticket
//   finalize. This finally tests 3 blocks/CU with a non-spilling kernel.
//   Expect: VGPR 128, WRITE ~10MB, FETCH 30-50MB, Occ ~30%, sim ~30-36us.
// ---------------------------------------------------------------------------

typedef int i32x8 __attribute__((ext_vector_type(8)));
typedef float f32x4 __attribute__((ext_vector_type(4)));

#define B_N 8192
#define D_K 512
#define ROWB 512  // bytes per fp8 row
#define INVT 14.285714285714286f
// (1/0.07) * log2(e)
#define SCALE_LOG2 20.609929155556622f

#if defined(__has_builtin) && __has_builtin(__builtin_amdgcn_exp2f)
#define FAST_EXP2(x) __builtin_amdgcn_exp2f(x)
#else
#define FAST_EXP2(x) exp2f(x)
#endif

union FragU {
  int4 h[2];
  i32x8 v;
};

static __device__ __forceinline__ void load16_to_lds(const void* g, void* l) {
  __builtin_amdgcn_global_load_lds(
      (const __attribute__((address_space(1))) unsigned int*)g,
      (__attribute__((address_space(3))) unsigned int*)l, 16, 0, 0);
}

// ---- K1: 4 waves/block, one wave per row; normalize fp32 -> fp8 e4m3 --------
// Also zeroes Z, S, ticket (ws is poisoned before every launch).
__global__ __launch_bounds__(256)
void norm_kernel(const float* __restrict__ x,
                 unsigned char* __restrict__ fQ,
                 float* __restrict__ Z,
                 float* __restrict__ S,
                 int* __restrict__ ticket) {
  const int row = blockIdx.x * 4 + (threadIdx.x >> 6);
  const int lane = threadIdx.x & 63;
  const float4* xr = (const float4*)(x + (size_t)row * D_K);
  float4 a = xr[2 * lane];
  float4 b = xr[2 * lane + 1];
  float s = a.x * a.x + a.y * a.y + a.z * a.z + a.w * a.w +
            b.x * b.x + b.y * b.y + b.z * b.z + b.w * b.w;
#pragma unroll
  for (int off = 1; off < 64; off <<= 1) s += __shfl_xor(s, off);
  const float inv = 1.0f / fmaxf(sqrtf(s), 1e-12f);
  int lo = 0, hi = 0;
  lo = __builtin_amdgcn_cvt_pk_fp8_f32(a.x * inv, a.y * inv, lo, false);
  lo = __builtin_amdgcn_cvt_pk_fp8_f32(a.z * inv, a.w * inv, lo, true);
  hi = __builtin_amdgcn_cvt_pk_fp8_f32(b.x * inv, b.y * inv, hi, false);
  hi = __builtin_amdgcn_cvt_pk_fp8_f32(b.z * inv, b.w * inv, hi, true);
  int2 p; p.x = lo; p.y = hi;
  ((int2*)(fQ + (size_t)row * ROWB))[lane] = p;
  if (lane == 0) Z[row] = 0.0f;
  if (blockIdx.x == 0 && threadIdx.x == 0) {
    S[0] = 0.0f;
    ticket[0] = 0;
  }
}

// ---- K2: upper-triangular fp8 similarity + softmax-denominator --------------
// grid (64,16): I = bx (flipped on odd by), b = by; tiles J in {J >= I,
// J == b mod 16}. 4 waves 2x2; wave owns 64x64 C via 4x4 frags of
// 16x16x128 MX-fp8 MFMA (scale=1). Granule layout per 128B chunk: slot s
// of row r holds global granule h(s^(r&7)), h(u)=2(u&3)+(u>>2); frag reads
// at slots (q)^swz,(q+4)^swz -> granules 2q,2q+1, zero conflicts.
// A K-planes double-buffered (plane kk+1 staged during phase kk, ROLLED
// loop); B single buffer staged at phase start; two __syncthreads/phase.
// LDS 48KB -> 3 blocks/CU; VGPR 128 (launch_bounds(256,2), no spill).
__global__ __launch_bounds__(256, 2)
void sim_kernel(const unsigned char* __restrict__ fQ,
                float* __restrict__ Z, float* __restrict__ T01,
                float* __restrict__ D) {
  __shared__ unsigned char ldsA[2][128 * 128];  // 32 KB: A plane dbuf
  __shared__ unsigned char ldsB[128 * 128];     // 16 KB

  const int tid = threadIdx.x;
  const int lane = tid & 63;
  const int w = tid >> 6;
  const int wm = w & 1;       // wave row strip (0/1) -> rows wm*64..
  const int wn = w >> 1;      // wave col strip (0/1) -> cols wn*64..
  const int bx = blockIdx.x, by = blockIdx.y;
  const int I = (by & 1) ? (63 - bx) : bx;     // row band index (paired)
  const int Jfirst = I + ((by - I) & 15);      // first J >= I, J==by (mod 16)
  if (Jfirst > 63) return;                     // no tiles for this block
  const int I0 = I * 128;

  // staging lane geometry: 8 rows x 8 slots(16B) per instruction.
  const int srow = lane >> 3;                 // 0..7
  const int sb = lane & 7;                    // dest slot
  const int su = sb ^ srow;
  const int sg = 2 * (su & 3) + (su >> 2);    // source granule
  const size_t sOff = (size_t)srow * ROWB + sg * 16;  // bytes

  // fragment-read lane geometry
  const int fr = lane & 15;   // M/N index within 16
  const int q = lane >> 4;    // quad -> k chunk of 32B
  const int swz = fr & 7;     // row&7 of the frag row

  const int raRow = (wm * 64 + fr) * 128;
  const unsigned char* rbBase = ldsB + (wn * 64 + fr) * 128;
  const int off0 = (q ^ swz) * 16;        // slot holding granule 2q
  const int off1 = ((q + 4) ^ swz) * 16;  // slot holding granule 2q+1

  // ---- prologue: stage A plane 0 into ldsA[0] ------------------------------
  {
    const unsigned char* gA = fQ + (size_t)(I0 + w * 32) * ROWB + sOff;
    unsigned char* lA = ldsA[0] + (w * 32) * 128;
#pragma unroll
    for (int rr = 0; rr < 32; rr += 8)
      load16_to_lds(gA + (size_t)rr * ROWB, lA + rr * 128);
  }

  float Zp[4][4];
#pragma unroll
  for (int m = 0; m < 4; ++m)
#pragma unroll
    for (int r = 0; r < 4; ++r) Zp[m][r] = 0.0f;

#pragma unroll 1
  for (int J = Jfirst; J < 64; J += 16) {
    const int J0 = J * 128;
    f32x4 acc[4][4];
#pragma unroll
    for (int m = 0; m < 4; ++m)
#pragma unroll
      for (int n = 0; n < 4; ++n) acc[m][n] = (f32x4){0.f, 0.f, 0.f, 0.f};

#pragma unroll 1
    for (int kk = 0; kk < 4; ++kk) {
      {  // B: 128 rows of chunk kk, wave stages rows w*32..+31 (4 instrs)
        const unsigned char* gB =
            fQ + (size_t)(J0 + w * 32) * ROWB + kk * 128 + sOff;
        unsigned char* lB = ldsB + (w * 32) * 128;
#pragma unroll
        for (int rr = 0; rr < 32; rr += 8)
          load16_to_lds(gB + (size_t)rr * ROWB, lB + rr * 128);
      }
      {  // A: plane (kk+1)&3 into the other buffer (read at phase kk+1;
         // that buffer's last readers finished at phase kk-1's barrier)
        const int p = (kk + 1) & 3;
        const unsigned char* gA =
            fQ + (size_t)(I0 + w * 32) * ROWB + p * 128 + sOff;
        unsigned char* lA = ldsA[(kk + 1) & 1] + (w * 32) * 128;
#pragma unroll
        for (int rr = 0; rr < 32; rr += 8)
          load16_to_lds(gA + (size_t)rr * ROWB, lA + rr * 128);
      }
      __syncthreads();  // drains vmcnt: B(kk) + A(kk+1) staged; A(kk) ready

      const unsigned char* raBase = ldsA[kk & 1] + raRow;
      i32x8 bv[4];
#pragma unroll
      for (int n = 0; n < 4; ++n) {
        const unsigned char* rb = rbBase + n * 16 * 128;
        FragU u;
        u.h[0] = *(const int4*)(rb + off0);
        u.h[1] = *(const int4*)(rb + off1);
        bv[n] = u.v;
      }
#pragma unroll
      for (int mh = 0; mh < 2; ++mh) {  // m-split: av[2] live, not av[4]
        i32x8 av[2];
#pragma unroll
        for (int m = 0; m < 2; ++m) {
          const unsigned char* ra = raBase + (mh * 2 + m) * 16 * 128;
          FragU u;
          u.h[0] = *(const int4*)(ra + off0);
          u.h[1] = *(const int4*)(ra + off1);
          av[m] = u.v;
        }
#pragma unroll
        for (int m = 0; m < 2; ++m)
#pragma unroll
          for (int n = 0; n < 4; ++n)
            acc[mh * 2 + m][n] = __builtin_amdgcn_mfma_scale_f32_16x16x128_f8f6f4(
                av[m], bv[n], acc[mh * 2 + m][n], 0, 0, 0, 127, 0, 127);
      }
      __syncthreads();  // all waves done reading ldsB / ldsA[(kk+1)&1]'s old
    }

    // T01: sim[0,c], sim[1,c] from rows 0,1 (band I==0 only; rows 0,1 live
    // in wm==0, frag m=0, q==0, r in {0,1}; col c = J0 + wn*64 + n*16 + fr)
    if (I == 0 && wm == 0) {
      if (q == 0) {
#pragma unroll
        for (int n = 0; n < 4; ++n) {
          const int col = J0 + wn * 64 + n * 16 + fr;
          T01[col * 2 + 0] = acc[0][n][0] * INVT;
          T01[col * 2 + 1] = acc[0][n][1] * INVT;
        }
      }
    }

    // D: diagonal dots, from the diagonal tile only
    if (J == I) {
#pragma unroll
      for (int m = 0; m < 4; ++m)
#pragma unroll
        for (int n = 0; n < 4; ++n) {
          const int col = J0 + wn * 64 + n * 16 + fr;
#pragma unroll
          for (int r = 0; r < 4; ++r) {
            const int row = I0 + wm * 64 + m * 16 + q * 4 + r;
            if (row == col) D[row] = acc[m][n][r];
          }
        }
    }

    // Z: row partials always (covers this tile's rows); column sums for
    // off-diag tiles (transpose contribution to Z[J-band]).
    const bool offd = (J != I);
#pragma unroll
    for (int n = 0; n < 4; ++n) {
      float cs = 0.0f;
#pragma unroll
      for (int m = 0; m < 4; ++m)
#pragma unroll
        for (int r = 0; r < 4; ++r) {
          const float e = FAST_EXP2((acc[m][n][r] - 1.0f) * SCALE_LOG2);
          Zp[m][r] += e;
          cs += e;
        }
      if (offd) {
        cs += __shfl_xor(cs, 16);
        cs += __shfl_xor(cs, 32);
        if (q == 0) atomicAdd(&Z[J0 + wn * 64 + n * 16 + fr], cs);
      }
    }
  }

  // row sums: reduce Zp across the 16 col-lanes, then atomicAdd
#pragma unroll
  for (int m = 0; m < 4; ++m)
#pragma unroll
    for (int r = 0; r < 4; ++r) {
      float v = Zp[m][r];
      v += __shfl_xor(v, 1);
      v += __shfl_xor(v, 2);
      v += __shfl_xor(v, 4);
      v += __shfl_xor(v, 8);
      if (fr == 0) atomicAdd(&Z[I0 + wm * 64 + m * 16 + q * 4 + r], v);
    }
}

// ---- K3: labels + exact-diagonal fixup + loss reduction (8 blocks) ----------
// 8 blocks x 1024 threads, 1 row each; block partial -> device atomicAdd;
// last block (ticket) writes the final scaled loss.
__global__ __launch_bounds__(1024)
void finalize_kernel(const float* __restrict__ Z,
                     const float* __restrict__ T01,
                     const float* __restrict__ D,
                     const int* __restrict__ ids,
                     const int* __restrict__ anchor,
                     float* __restrict__ S,
                     int* __restrict__ ticket,
                     float* __restrict__ out) {
  __shared__ float red[16];
  const int t = threadIdx.x;
  const int row = blockIdx.x * 1024 + t;
  const int anchor_id = ids[anchor[0]];
  const int sameLast = (ids[B_N - 1] == anchor_id);
  const int samePrev = (ids[B_N - 2] == anchor_id);
  const float z = Z[row];
  const float d = D[row];
  const float t0 = T01[row * 2 + 0];
  const float t1 = T01[row * 2 + 1];
  const int id = ids[row];

  const int same_i = (id == anchor_id);
  const int lab = (row < B_N - 1) ? (same_i & sameLast) : (sameLast & samePrev);
  const float tt = lab ? t1 : t0;
  // replace quantized diag contribution with the exact value exp(0)=1
  const float Zc = z - FAST_EXP2((d - 1.0f) * SCALE_LOG2) + 1.0f;
  float sum = tt - (INVT + logf(Zc));

#pragma unroll
  for (int off = 1; off < 64; off <<= 1) sum += __shfl_xor(sum, off);
  if ((t & 63) == 0) red[t >> 6] = sum;
  __syncthreads();
  if (t < 64) {
    float v = (t < 16) ? red[t] : 0.0f;
#pragma unroll
    for (int off = 1; off < 16; off <<= 1) v += __shfl_xor(v, off);
    if (t == 0) {
      atomicAdd(S, v);
      __threadfence();
      const int old = atomicAdd(ticket, 1);
      if (old == 7) {
        const float tot = atomicAdd(S, 0.0f);  // device-scope coherent read
        out[0] = -tot / (float)B_N;
      }
    }
  }
}

// ---------------------------------------------------------------------------
extern "C" void kernel_launch(void* const* d_in, const int* in_sizes, int n_in,
                              void* d_out, int out_size, void* d_ws, size_t ws_size,
                              hipStream_t stream) {
  const float* x = (const float*)d_in[0];
  const int* ids = (const int*)d_in[1];
  const int* anchor = (const int*)d_in[2];
  float* out = (float*)d_out;

  unsigned char* fQ = (unsigned char*)d_ws;                    // 4 MB fp8
  float* Z = (float*)((char*)d_ws + (size_t)B_N * ROWB);       // 32 KB
  float* T01 = Z + B_N;                                        // 64 KB
  float* D = T01 + 2 * B_N;                                    // 32 KB
  float* S = D + B_N;                                          // 4 B
  int* ticket = (int*)(S + 1);                                 // 4 B

  norm_kernel<<<B_N / 4, 256, 0, stream>>>(x, fQ, Z, S, ticket);
  sim_kernel<<<dim3(64, 16), 256, 0, stream>>>(fQ, Z, T01, D);
  finalize_kernel<<<8, 1024, 0, stream>>>(Z, T01, D, ids, anchor, S, ticket, out);
}